// Round 2
// baseline (299.184 us; speedup 1.0000x reference)
//
#include <hip/hip_runtime.h>
#include <stdint.h>

#define N_NODES 100000
#define N_EDGES 1600000
#define IN_F 128
#define OUT_F 32

#define SCAN_BLK 256
#define NBLK_SCAN ((N_NODES + SCAN_BLK - 1) / SCAN_BLK)   // 391

// ---------------------------------------------------------------------------
// GEMM v2: support = x @ W   [N,128]x[128,32] -> [N,32]
// 256 threads/block, 64 rows/block. Per-thread tile: 2 rows x 4 features.
// All LDS reads are b128 (k-unroll 4). xs stride 132 floats: 16B-aligned,
// row-group bank offset 8 -> worst 2-way conflict (free per m136).
// ---------------------------------------------------------------------------
__global__ __launch_bounds__(256) void gcn_gemm2(const float* __restrict__ x,
                                                 const float* __restrict__ w,
                                                 float* __restrict__ support) {
    __shared__ float ws[IN_F][OUT_F];      // 16 KB, [k][f] row-major == w layout
    __shared__ float xs[64][IN_F + 4];     // stride 132 floats
    const int tid = threadIdx.x;
    const int rowBase = blockIdx.x * 64;

    // Load W: 4096 floats = 1024 float4, 4 per thread, coalesced.
    {
        float* wsf = &ws[0][0];
        #pragma unroll
        for (int chunk = 0; chunk < 4; ++chunk) {
            const int i = chunk * 1024 + tid * 4;
            *reinterpret_cast<float4*>(wsf + i) =
                *reinterpret_cast<const float4*>(&w[i]);
        }
    }
    // Load 64 rows of x: 8192 floats = 2048 float4, 8 per thread, coalesced.
    #pragma unroll
    for (int chunk = 0; chunk < 8; ++chunk) {
        const int idx = chunk * 1024 + tid * 4;
        const int r = idx >> 7;
        const int c = idx & 127;
        if (rowBase + r < N_NODES) {
            *reinterpret_cast<float4*>(&xs[r][c]) =
                *reinterpret_cast<const float4*>(&x[(size_t)(rowBase + r) * IN_F + c]);
        }
    }
    __syncthreads();

    const int fg = tid & 7;        // feature group: f0..f0+3
    const int rg = tid >> 3;       // row group: 2 rows
    const int f0 = fg * 4;
    const int r0 = rg * 2;

    float acc[2][4] = {{0.f, 0.f, 0.f, 0.f}, {0.f, 0.f, 0.f, 0.f}};
    for (int k0 = 0; k0 < IN_F; k0 += 4) {
        const float4 xa = *reinterpret_cast<const float4*>(&xs[r0][k0]);
        const float4 xb = *reinterpret_cast<const float4*>(&xs[r0 + 1][k0]);
        const float xav[4] = {xa.x, xa.y, xa.z, xa.w};
        const float xbv[4] = {xb.x, xb.y, xb.z, xb.w};
        #pragma unroll
        for (int j = 0; j < 4; ++j) {
            const float4 wv = *reinterpret_cast<const float4*>(&ws[k0 + j][f0]);
            acc[0][0] += xav[j] * wv.x;  acc[0][1] += xav[j] * wv.y;
            acc[0][2] += xav[j] * wv.z;  acc[0][3] += xav[j] * wv.w;
            acc[1][0] += xbv[j] * wv.x;  acc[1][1] += xbv[j] * wv.y;
            acc[1][2] += xbv[j] * wv.z;  acc[1][3] += xbv[j] * wv.w;
        }
    }
    #pragma unroll
    for (int i = 0; i < 2; ++i) {
        const int row = rowBase + r0 + i;
        if (row < N_NODES) {
            float4 v;
            v.x = acc[i][0]; v.y = acc[i][1]; v.z = acc[i][2]; v.w = acc[i][3];
            *reinterpret_cast<float4*>(&support[(size_t)row * OUT_F + f0]) = v;
        }
    }
}

// ---------------------------------------------------------------------------
// CSR build: histogram -> 3-phase exclusive scan -> cursor scatter
// ---------------------------------------------------------------------------
__global__ __launch_bounds__(256) void gcn_hist(const int* __restrict__ row,
                                                int* __restrict__ deg) {
    const int e = blockIdx.x * 256 + threadIdx.x;
    if (e < N_EDGES) atomicAdd(&deg[row[e]], 1);
}

__global__ __launch_bounds__(256) void scan_a(const int* __restrict__ deg,
                                              int* __restrict__ ptr,
                                              int* __restrict__ bsum) {
    __shared__ int s[256];
    const int i = blockIdx.x * 256 + threadIdx.x;
    const int v = (i < N_NODES) ? deg[i] : 0;
    s[threadIdx.x] = v;
    __syncthreads();
    for (int off = 1; off < 256; off <<= 1) {
        const int t = (threadIdx.x >= off) ? s[threadIdx.x - off] : 0;
        __syncthreads();
        s[threadIdx.x] += t;
        __syncthreads();
    }
    if (i < N_NODES) ptr[i] = s[threadIdx.x] - v;   // block-local exclusive
    if (threadIdx.x == 255) bsum[blockIdx.x] = s[255];
}

__global__ __launch_bounds__(512) void scan_b(int* __restrict__ bsum) {
    __shared__ int s[512];
    const int v = (threadIdx.x < NBLK_SCAN) ? bsum[threadIdx.x] : 0;
    s[threadIdx.x] = v;
    __syncthreads();
    for (int off = 1; off < 512; off <<= 1) {
        const int t = (threadIdx.x >= off) ? s[threadIdx.x - off] : 0;
        __syncthreads();
        s[threadIdx.x] += t;
        __syncthreads();
    }
    if (threadIdx.x < NBLK_SCAN) bsum[threadIdx.x] = s[threadIdx.x] - v;  // exclusive
}

__global__ __launch_bounds__(256) void scan_c(int* __restrict__ ptr,
                                              const int* __restrict__ bsum,
                                              int* __restrict__ cursor) {
    const int i = blockIdx.x * 256 + threadIdx.x;
    if (i < N_NODES) {
        const int p = ptr[i] + bsum[blockIdx.x];
        ptr[i] = p;
        cursor[i] = p;
    }
    if (i == 0) ptr[N_NODES] = N_EDGES;
}

__global__ __launch_bounds__(256) void gcn_escatter(const int* __restrict__ row,
                                                    const int* __restrict__ col,
                                                    const float* __restrict__ val,
                                                    int* __restrict__ cursor,
                                                    long long* __restrict__ epk) {
    const int e = blockIdx.x * 256 + threadIdx.x;
    if (e < N_EDGES) {
        const int r = row[e];
        const int p = atomicAdd(&cursor[r], 1);
        const long long pk = ((long long)__float_as_int(val[e]) << 32) |
                             (long long)(uint32_t)col[e];
        epk[p] = pk;
    }
}

// ---------------------------------------------------------------------------
// Gather: out[r][f] = bias[f] + sum_{i in [ptr[r],ptr[r+1])} val_i * support[col_i][f]
// 32 lanes per row (one per feature), 8 rows per block. Writes out exactly once.
// ---------------------------------------------------------------------------
__global__ __launch_bounds__(256) void gcn_gather(const int* __restrict__ ptr,
                                                  const long long* __restrict__ epk,
                                                  const float* __restrict__ support,
                                                  const float* __restrict__ bias,
                                                  float* __restrict__ out) {
    const int f = threadIdx.x & 31;
    const int rg = threadIdx.x >> 5;
    const int r = blockIdx.x * 8 + rg;
    if (r >= N_NODES) return;
    const int s = ptr[r];
    const int e = ptr[r + 1];
    float acc = bias[f];
    for (int i = s; i < e; ++i) {
        const long long pk = epk[i];                       // wave-broadcast 8B load
        const int c = (int)(uint32_t)(pk & 0xffffffffLL);
        const float v = __int_as_float((int)(pk >> 32));
        acc += v * support[(size_t)c * OUT_F + f];         // coalesced 128B gather
    }
    out[(size_t)r * OUT_F + f] = acc;
}

// ---------------------------------------------------------------------------
// Fallback path (if ws too small for CSR): round-1 atomic scatter
// ---------------------------------------------------------------------------
__global__ __launch_bounds__(256) void gcn_bias_init(const float* __restrict__ bias,
                                                     float* __restrict__ out) {
    const int i = blockIdx.x * 256 + threadIdx.x;
    if (i < N_NODES * OUT_F) out[i] = bias[i & 31];
}

__global__ __launch_bounds__(256) void gcn_scatter(const int* __restrict__ row,
                                                   const int* __restrict__ col,
                                                   const float* __restrict__ val,
                                                   const float* __restrict__ support,
                                                   float* __restrict__ out) {
    const int f = threadIdx.x & 31;
    const int grp = threadIdx.x >> 5;
    long long e = (long long)blockIdx.x * 8 + grp;
    const long long stride = (long long)gridDim.x * 8;
    for (; e < N_EDGES; e += stride) {
        const int r = row[e];
        const int c = col[e];
        const float v = val[e];
        const float s = support[(size_t)c * OUT_F + f];
        atomicAdd(&out[(size_t)r * OUT_F + f], v * s);
    }
}

extern "C" void kernel_launch(void* const* d_in, const int* in_sizes, int n_in,
                              void* d_out, int out_size, void* d_ws, size_t ws_size,
                              hipStream_t stream) {
    const float* x       = (const float*)d_in[0];
    const int*   adj_row = (const int*)d_in[1];
    const int*   adj_col = (const int*)d_in[2];
    const float* adj_val = (const float*)d_in[3];
    const float* weight  = (const float*)d_in[4];
    const float* bias    = (const float*)d_in[5];
    float* out = (float*)d_out;

    char* ws = (char*)d_ws;
    const size_t SUPPORT_B = (size_t)N_NODES * OUT_F * 4;       // 12,800,000
    const size_t EPK_B     = (size_t)N_EDGES * 8;               // 12,800,000
    const size_t PTR_B     = ((size_t)(N_NODES + 1) * 4 + 255) & ~(size_t)255;  // 400,128
    const size_t CUR_B     = ((size_t)N_NODES * 4 + 255) & ~(size_t)255;        // 400,128
    const size_t BSUM_B    = 4096;
    const size_t NEED = SUPPORT_B + EPK_B + PTR_B + CUR_B + BSUM_B;

    float* support = (float*)(ws);
    long long* epk = (long long*)(ws + SUPPORT_B);
    int* ptr       = (int*)(ws + SUPPORT_B + EPK_B);
    int* cursor    = (int*)(ws + SUPPORT_B + EPK_B + PTR_B);
    int* bsum      = (int*)(ws + SUPPORT_B + EPK_B + PTR_B + CUR_B);

    // 1) support = x @ W
    gcn_gemm2<<<(N_NODES + 63) / 64, 256, 0, stream>>>(x, weight, support);

    if (ws_size >= NEED) {
        // 2) CSR build
        hipMemsetAsync(cursor, 0, (size_t)N_NODES * 4, stream);
        gcn_hist<<<(N_EDGES + 255) / 256, 256, 0, stream>>>(adj_row, cursor);
        scan_a<<<NBLK_SCAN, 256, 0, stream>>>(cursor, ptr, bsum);
        scan_b<<<1, 512, 0, stream>>>(bsum);
        scan_c<<<NBLK_SCAN, 256, 0, stream>>>(ptr, bsum, cursor);
        gcn_escatter<<<(N_EDGES + 255) / 256, 256, 0, stream>>>(adj_row, adj_col,
                                                                adj_val, cursor, epk);
        // 3) row-parallel gather (bias fused, single write per output)
        gcn_gather<<<N_NODES / 8, 256, 0, stream>>>(ptr, epk, support, bias, out);
    } else {
        // Fallback: atomic scatter path
        gcn_bias_init<<<(N_NODES * OUT_F + 255) / 256, 256, 0, stream>>>(bias, out);
        gcn_scatter<<<8192, 256, 0, stream>>>(adj_row, adj_col, adj_val, support, out);
    }
}